// Round 5
// baseline (1935.357 us; speedup 1.0000x reference)
//
#include <hip/hip_runtime.h>

// ---------------------------------------------------------------------------
// GCN, 6 layers, N=1M nodes, E=16M edges.
// R10: four rounds (R5/R6/R8/R9) all sit at 262-266us across occupancy
// 35-68%, plain/asm-pinned schedules, and 280-560MB HBM traffic -> the
// gather path is capped at ~10cy/edge/CU (MSHR ~50 outstanding misses, or
// equivalently ~60B of L2 line-fill per 16B gather). Only lever left:
// RAISE LINE REUSE so gathers hit L2. R5's src-superblock sweep assumed
// blocks stay in lockstep; they drift, windows evict, lines refetch ~4x.
// Fix: grid-wide phase barrier between the 8 src windows. 245 blocks x 16
// waves = max 2 blocks/CU -> all co-resident -> spin barrier is safe; it
// carries NO data dependency (read-only src, block-private LDS accum) so
// it is perf-only. Dead asm pipeline dropped (VGPR=44 proved it spilled;
// schedule proven value-neutral). nt packed loads + nt stores kept (R9:
// -38% FETCH). Predict: layer3 FETCH 260->~100MB, dur 265->100-150us.
// packed edge = (src<<12)|(dst&4095); key = (dst>>12)<<3 | (src>>17).
// ---------------------------------------------------------------------------

#define BT 256            // build-kernel block size
#define NBLK 256          // partition blocks
#define BSHIFT 12         // 4096 nodes per dst bucket
#define BSIZE 4096
#define LMASK 4095
#define SSH 17            // src super-block shift (128K nodes = 2MB float4 window)
#define NPHASE 8          // src superblocks = phases
#define NBINS 2048        // (dst_bucket<<3)|src_sb, padded (real: 245*8=1960)
#define M (NBLK * NBINS)  // 524288
#define BTL 1024          // layer-kernel block size
#define NBAR 64           // barrier counters (6 layers x 8 phases, padded)

typedef float __attribute__((ext_vector_type(4))) f32x4;
typedef unsigned int __attribute__((ext_vector_type(4))) u32x4;

__device__ __forceinline__ int edge_key(int s, int d) {
  return ((d >> BSHIFT) << 3) | (s >> SSH);
}

// s0 = feat * norm
__global__ void k_init(const float* __restrict__ feat, const float* __restrict__ norm,
                       float* __restrict__ s0, int N) {
  int i = blockIdx.x * BT + threadIdx.x;
  if (i < N) s0[i] = feat[i] * norm[i];
}

// zero the phase-barrier counters (runs once per captured launch sequence)
__global__ void k_zerobar(int* __restrict__ bars) {
  if (threadIdx.x < NBAR) bars[threadIdx.x] = 0;
}

// P1: per-block LDS histogram of (dst_bucket, src_sb) bins
__global__ void k_phist(const int* __restrict__ src, const int* __restrict__ dst,
                        int* __restrict__ histB, int E, int chunk) {
  __shared__ int h[NBINS];
  for (int i = threadIdx.x; i < NBINS; i += BT) h[i] = 0;
  __syncthreads();
  int b = blockIdx.x;
  int beg = b * chunk, end = min(beg + chunk, E);
  int i = beg + (int)threadIdx.x * 4;  // beg is 16B-aligned (chunk % 4 == 0)
  for (; i + 3 < end; i += BT * 4) {
    int4 u = *(const int4*)(src + i);
    int4 v = *(const int4*)(dst + i);
    atomicAdd(&h[edge_key(u.x, v.x)], 1);
    atomicAdd(&h[edge_key(u.y, v.y)], 1);
    atomicAdd(&h[edge_key(u.z, v.z)], 1);
    atomicAdd(&h[edge_key(u.w, v.w)], 1);
  }
  for (; i < end; ++i) atomicAdd(&h[edge_key(src[i], dst[i])], 1);
  __syncthreads();
  for (int k = threadIdx.x; k < NBINS; k += BT) histB[b * NBINS + k] = h[k];
}

// Tiled transpose: in[R][C] -> out[C][R]. R,C multiples of 64. grid(C/64,R/64)
__global__ void k_transp(const int* __restrict__ in, int* __restrict__ out, int R, int C) {
  __shared__ int tile[64][65];
  int c0 = blockIdx.x * 64, r0 = blockIdx.y * 64;
  int tx = threadIdx.x & 63, ty = threadIdx.x >> 6;  // 64 x 4
  for (int j = 0; j < 16; ++j) {
    int r = ty + j * 4;
    tile[r][tx] = in[(r0 + r) * C + c0 + tx];
  }
  __syncthreads();
  for (int j = 0; j < 16; ++j) {
    int r = ty + j * 4;
    out[(c0 + r) * R + r0 + tx] = tile[tx][r];
  }
}

// scan A: per-block sums
__global__ void k_blockSum(const int* __restrict__ data, int* __restrict__ partial, int Mlen) {
  __shared__ int tmp[BT];
  int i = blockIdx.x * BT + threadIdx.x;
  tmp[threadIdx.x] = (i < Mlen) ? data[i] : 0;
  __syncthreads();
  for (int off = BT / 2; off > 0; off >>= 1) {
    if (threadIdx.x < off) tmp[threadIdx.x] += tmp[threadIdx.x + off];
    __syncthreads();
  }
  if (threadIdx.x == 0) partial[blockIdx.x] = tmp[0];
}

// scan B: exclusive scan of partials in place (single block)
__global__ void k_scanPartials(int* __restrict__ partial, int nb) {
  __shared__ int tmp[BT];
  __shared__ int carry;
  int t = threadIdx.x;
  if (t == 0) carry = 0;
  __syncthreads();
  for (int base = 0; base < nb; base += BT) {
    int i = base + t;
    int v = (i < nb) ? partial[i] : 0;
    tmp[t] = v;
    __syncthreads();
    for (int off = 1; off < BT; off <<= 1) {
      int x = 0;
      if (t >= off) x = tmp[t - off];
      __syncthreads();
      tmp[t] += x;
      __syncthreads();
    }
    if (i < nb) partial[i] = tmp[t] - v + carry;
    __syncthreads();
    if (t == BT - 1) carry += tmp[BT - 1];
    __syncthreads();
  }
}

// scan C: final exclusive scan in place
__global__ void k_scanFinal(int* __restrict__ data, const int* __restrict__ partial, int Mlen) {
  __shared__ int tmp[BT];
  int t = threadIdx.x;
  int i = blockIdx.x * BT + t;
  int v = (i < Mlen) ? data[i] : 0;
  tmp[t] = v;
  __syncthreads();
  for (int off = 1; off < BT; off <<= 1) {
    int x = 0;
    if (t >= off) x = tmp[t - off];
    __syncthreads();
    tmp[t] += x;
    __syncthreads();
  }
  if (i < Mlen) data[i] = tmp[t] - v + partial[blockIdx.x];
}

// P2: scatter packed edges with per-block LDS cursors
__global__ void k_pscatter(const int* __restrict__ src, const int* __restrict__ dst,
                           const int* __restrict__ scanT, unsigned int* __restrict__ packed,
                           int E, int chunk) {
  __shared__ int cur[NBINS];
  int b = blockIdx.x;
  for (int k = threadIdx.x; k < NBINS; k += BT) cur[k] = scanT[b * NBINS + k];
  __syncthreads();
  int beg = b * chunk, end = min(beg + chunk, E);
  int i = beg + (int)threadIdx.x * 4;
  for (; i + 3 < end; i += BT * 4) {
    int4 u = *(const int4*)(src + i);
    int4 v = *(const int4*)(dst + i);
    int p;
    p = atomicAdd(&cur[edge_key(u.x, v.x)], 1);
    packed[p] = ((unsigned)u.x << BSHIFT) | (unsigned)(v.x & LMASK);
    p = atomicAdd(&cur[edge_key(u.y, v.y)], 1);
    packed[p] = ((unsigned)u.y << BSHIFT) | (unsigned)(v.y & LMASK);
    p = atomicAdd(&cur[edge_key(u.z, v.z)], 1);
    packed[p] = ((unsigned)u.z << BSHIFT) | (unsigned)(v.z & LMASK);
    p = atomicAdd(&cur[edge_key(u.w, v.w)], 1);
    packed[p] = ((unsigned)u.w << BSHIFT) | (unsigned)(v.w & LMASK);
  }
  for (; i < end; ++i) {
    int p = atomicAdd(&cur[edge_key(src[i], dst[i])], 1);
    packed[p] = ((unsigned)src[i] << BSHIFT) | (unsigned)(dst[i] & LMASK);
  }
}

// --- layer kernels: one block per dst bucket, 8 barrier-locked src phases ---
// bin (k,p) edge range = [scanT[8k+p], scanT[8k+p+1])

// Perf-only grid barrier between src-window phases. All gridDim.x blocks are
// co-resident (16 waves/block -> max 2 blocks/CU; 245 <= 512 slots), so the
// spin cannot deadlock. No fences needed: no cross-block data dependency.
__device__ __forceinline__ void phase_bar(int* ctr, int target) {
  __syncthreads();
  if (threadIdx.x == 0) {
    __hip_atomic_fetch_add(ctr, 1, __ATOMIC_RELAXED, __HIP_MEMORY_SCOPE_AGENT);
    while (__hip_atomic_load(ctr, __ATOMIC_RELAXED, __HIP_MEMORY_SCOPE_AGENT) < target) {
      __builtin_amdgcn_s_sleep(8);
    }
  }
  __syncthreads();
}

#define NTL4(ptr) __builtin_nontemporal_load((const u32x4*)(ptr))

#define ACC3(p)                                             \
  {                                                         \
    unsigned pp = (p);                                      \
    float4 m = ((const float4*)sPrev)[pp >> BSHIFT];        \
    int loc = pp & LMASK;                                   \
    atomicAdd(&a0[loc], m.x);                               \
    atomicAdd(&a1[loc], m.y);                               \
    atomicAdd(&a2[loc], m.z);                               \
  }

#define ACC1(p)                                             \
  {                                                         \
    unsigned pp = (p);                                      \
    atomicAdd(&a[pp & LMASK], sIn[pp >> BSHIFT]);           \
  }

// Per-phase edge sweep (simple verified loop; ~8 edges/thread/phase)
#define PHASE_LOOP(ACC)                                                   \
  for (int p = 0; p < NPHASE; ++p) {                                      \
    int pbeg = scanT[base + p], pend = scanT[base + p + 1];               \
    int abeg = min(pend, (pbeg + 3) & ~3);                                \
    int t0 = pbeg + (int)threadIdx.x;                                     \
    if (t0 < abeg) ACC(packed[t0]);                                       \
    int i = abeg + (int)threadIdx.x * 4;                                  \
    for (; i + 3 < pend; i += BTL * 4) {                                  \
      u32x4 p4 = NTL4(packed + i);                                        \
      ACC(p4.x) ACC(p4.y) ACC(p4.z) ACC(p4.w)                             \
    }                                                                     \
    for (; i < pend; ++i) ACC(packed[i]);                                 \
    if (p < NPHASE - 1) phase_bar(bar + p, (int)gridDim.x);               \
  }

// Layer 1 (1->3)
__global__ __launch_bounds__(BTL, 4) void k_layer1(
    const int* __restrict__ scanT, const unsigned int* __restrict__ packed,
    const float* __restrict__ sIn, const float* __restrict__ norm,
    const float* __restrict__ W1, const float* __restrict__ b1,
    float* __restrict__ sNext, int* __restrict__ bar, int N) {
  __shared__ float a[BSIZE];
  int k = blockIdx.x;
  for (int ii = threadIdx.x; ii < BSIZE; ii += BTL) a[ii] = 0.0f;
  int base = k << 3;
  __syncthreads();
  PHASE_LOOP(ACC1)
  __syncthreads();
  int node0 = k << BSHIFT;
  for (int tt = threadIdx.x; tt < BSIZE; tt += BTL) {
    int node = node0 + tt;
    if (node >= N) break;
    float n = __builtin_nontemporal_load(norm + node);
    float pre = a[tt] * n;
    float h0 = fmaxf(0.0f, pre * W1[0] + b1[0]);
    float h1 = fmaxf(0.0f, pre * W1[1] + b1[1]);
    float h2 = fmaxf(0.0f, pre * W1[2] + b1[2]);
    f32x4 o = {h0 * n, h1 * n, h2 * n, 0.0f};
    __builtin_nontemporal_store(o, (f32x4*)sNext + node);
  }
}

// Layers 2-4 (3->3)
__global__ __launch_bounds__(BTL, 4) void k_layer3(
    const int* __restrict__ scanT, const unsigned int* __restrict__ packed,
    const float* __restrict__ sPrev, const float* __restrict__ norm,
    const float* __restrict__ W, const float* __restrict__ bias,
    float* __restrict__ sNext, int* __restrict__ bar, int N) {
  __shared__ float a0[BSIZE], a1[BSIZE], a2[BSIZE];
  int k = blockIdx.x;
  for (int ii = threadIdx.x; ii < BSIZE; ii += BTL) { a0[ii] = 0.0f; a1[ii] = 0.0f; a2[ii] = 0.0f; }
  int base = k << 3;
  __syncthreads();
  PHASE_LOOP(ACC3)
  __syncthreads();
  int node0 = k << BSHIFT;
  for (int tt = threadIdx.x; tt < BSIZE; tt += BTL) {
    int node = node0 + tt;
    if (node >= N) break;
    float n = __builtin_nontemporal_load(norm + node);
    float x0 = a0[tt] * n, x1 = a1[tt] * n, x2 = a2[tt] * n;
    float h0 = fmaxf(0.0f, x0 * W[0] + x1 * W[3] + x2 * W[6] + bias[0]);
    float h1 = fmaxf(0.0f, x0 * W[1] + x1 * W[4] + x2 * W[7] + bias[1]);
    float h2 = fmaxf(0.0f, x0 * W[2] + x1 * W[5] + x2 * W[8] + bias[2]);
    f32x4 o = {h0 * n, h1 * n, h2 * n, 0.0f};
    __builtin_nontemporal_store(o, (f32x4*)sNext + node);
  }
}

// Layer 5 (3->3) + layer-6 pre-transform: sB = (relu(agg*n @ W5 + b5) @ W6) * n
__global__ __launch_bounds__(BTL, 4) void k_layer5(
    const int* __restrict__ scanT, const unsigned int* __restrict__ packed,
    const float* __restrict__ sPrev, const float* __restrict__ norm,
    const float* __restrict__ W5, const float* __restrict__ b5,
    const float* __restrict__ W6, float* __restrict__ sB, int* __restrict__ bar, int N) {
  __shared__ float a0[BSIZE], a1[BSIZE], a2[BSIZE];
  int k = blockIdx.x;
  for (int ii = threadIdx.x; ii < BSIZE; ii += BTL) { a0[ii] = 0.0f; a1[ii] = 0.0f; a2[ii] = 0.0f; }
  int base = k << 3;
  __syncthreads();
  PHASE_LOOP(ACC3)
  __syncthreads();
  int node0 = k << BSHIFT;
  for (int tt = threadIdx.x; tt < BSIZE; tt += BTL) {
    int node = node0 + tt;
    if (node >= N) break;
    float n = __builtin_nontemporal_load(norm + node);
    float x0 = a0[tt] * n, x1 = a1[tt] * n, x2 = a2[tt] * n;
    float h0 = fmaxf(0.0f, x0 * W5[0] + x1 * W5[3] + x2 * W5[6] + b5[0]);
    float h1 = fmaxf(0.0f, x0 * W5[1] + x1 * W5[4] + x2 * W5[7] + b5[1]);
    float h2 = fmaxf(0.0f, x0 * W5[2] + x1 * W5[5] + x2 * W5[8] + b5[2]);
    float v = (h0 * W6[0] + h1 * W6[1] + h2 * W6[2]) * n;
    __builtin_nontemporal_store(v, sB + node);
  }
}

// Layer 6 (scalar): out = relu(agg * n + b6)
__global__ __launch_bounds__(BTL, 4) void k_layer6(
    const int* __restrict__ scanT, const unsigned int* __restrict__ packed,
    const float* __restrict__ sIn, const float* __restrict__ norm,
    const float* __restrict__ b6, float* __restrict__ out, int* __restrict__ bar, int N) {
  __shared__ float a[BSIZE];
  int k = blockIdx.x;
  for (int ii = threadIdx.x; ii < BSIZE; ii += BTL) a[ii] = 0.0f;
  int base = k << 3;
  __syncthreads();
  PHASE_LOOP(ACC1)
  __syncthreads();
  int node0 = k << BSHIFT;
  for (int tt = threadIdx.x; tt < BSIZE; tt += BTL) {
    int node = node0 + tt;
    if (node >= N) break;
    float v = fmaxf(0.0f, a[tt] * __builtin_nontemporal_load(norm + node) + b6[0]);
    __builtin_nontemporal_store(v, out + node);
  }
}

extern "C" void kernel_launch(void* const* d_in, const int* in_sizes, int n_in,
                              void* d_out, int out_size, void* d_ws, size_t ws_size,
                              hipStream_t stream) {
  const float* feat = (const float*)d_in[0];
  const float* norm = (const float*)d_in[1];
  const int* src = (const int*)d_in[2];
  const int* dst = (const int*)d_in[3];
  const float* W1 = (const float*)d_in[4];
  const float* b1 = (const float*)d_in[5];
  const float* W2 = (const float*)d_in[6];
  const float* b2 = (const float*)d_in[7];
  const float* W3 = (const float*)d_in[8];
  const float* b3 = (const float*)d_in[9];
  const float* W4 = (const float*)d_in[10];
  const float* b4 = (const float*)d_in[11];
  const float* W5 = (const float*)d_in[12];
  const float* b5 = (const float*)d_in[13];
  const float* W6 = (const float*)d_in[14];
  const float* b6 = (const float*)d_in[15];
  float* out = (float*)d_out;

  const int N = in_sizes[0];
  const int E = in_sizes[2];
  const int nbNode = (N + BT - 1) / BT;
  const int nBkt = (N + BSIZE - 1) >> BSHIFT;                 // 245
  const int chunk = (((E + NBLK - 1) / NBLK) + 3) & ~3;       // 16B-aligned chunks

  // Workspace: packed[E] | scanT[M] | partial[M/BT] | bars[NBAR] | s0B[N]f |
  //            sA[4N]f | sA2[4N]f (~102 MB). histB/histT (2MB+2MB) alias sA:
  //            dead before k_layer1 first writes sA.
  unsigned int* packed = (unsigned int*)d_ws;
  int* scanT = (int*)(packed + (size_t)E);
  int* partial = scanT + (size_t)M;
  int* bars = partial + M / BT;
  float* s0B = (float*)(bars + NBAR);
  float* sA = s0B + (size_t)N;
  float* sA2 = sA + (size_t)4 * N;
  int* histB = (int*)sA;            // build-phase only
  int* histT = histB + (size_t)M;   // build-phase only

  // --- Build (dst_bucket, src_superblock)-ordered edge list ---
  k_init<<<nbNode, BT, 0, stream>>>(feat, norm, s0B, N);
  k_zerobar<<<1, 64, 0, stream>>>(bars);
  k_phist<<<NBLK, BT, 0, stream>>>(src, dst, histB, E, chunk);
  {
    dim3 g1(NBINS / 64, NBLK / 64);  // histB[NBLK][NBINS] -> histT[NBINS][NBLK]
    k_transp<<<g1, BT, 0, stream>>>(histB, histT, NBLK, NBINS);
  }
  k_blockSum<<<M / BT, BT, 0, stream>>>(histT, partial, M);
  k_scanPartials<<<1, BT, 0, stream>>>(partial, M / BT);
  k_scanFinal<<<M / BT, BT, 0, stream>>>(histT, partial, M);
  {
    dim3 g2(NBLK / 64, NBINS / 64);  // histT[NBINS][NBLK] (scanned) -> scanT[NBLK][NBINS]
    k_transp<<<g2, BT, 0, stream>>>(histT, scanT, NBINS, NBLK);
  }
  k_pscatter<<<NBLK, BT, 0, stream>>>(src, dst, scanT, packed, E, chunk);

  // --- 6 fused layers, each with 8 barrier-locked src-window phases ---
  k_layer1<<<nBkt, BTL, 0, stream>>>(scanT, packed, s0B, norm, W1, b1, sA, bars + 0, N);
  k_layer3<<<nBkt, BTL, 0, stream>>>(scanT, packed, sA, norm, W2, b2, sA2, bars + 8, N);
  k_layer3<<<nBkt, BTL, 0, stream>>>(scanT, packed, sA2, norm, W3, b3, sA, bars + 16, N);
  k_layer3<<<nBkt, BTL, 0, stream>>>(scanT, packed, sA, norm, W4, b4, sA2, bars + 24, N);
  k_layer5<<<nBkt, BTL, 0, stream>>>(scanT, packed, sA2, norm, W5, b5, W6, s0B, bars + 32, N);
  k_layer6<<<nBkt, BTL, 0, stream>>>(scanT, packed, s0B, norm, b6, out, bars + 40, N);
}